// Round 1
// baseline (3014.516 us; speedup 1.0000x reference)
//
#include <hip/hip_runtime.h>

#define NHID   1024
#define BATCH  128
#define LSTEPS 1000
#define DTC    0.042f
#define THETA  1.0f
#define TAUM   20.0f

// One block per batch element; thread h owns hidden unit h.
// Spike vectors are 16 x u64 bitmasks in LDS; the binary-spike matmuls become
// ascending-j sparse row accumulations (bit-identical to sequential dense f32).
__global__ __launch_bounds__(1024) void coesn_sim(
    const float* __restrict__ x,        // (B, L, 1)
    const float* __restrict__ x2h,      // (1, H)
    const float* __restrict__ h2h,      // (H, H)
    const float* __restrict__ bias,     // (H)
    const float* __restrict__ lif2hrf,  // (H, H)
    const float* __restrict__ gamma_,   // (H)
    const float* __restrict__ eps_,     // (H)
    float* __restrict__ out,            // (B, 3H) features + 3 scalars (written by finalize)
    unsigned int* __restrict__ ws)      // (B, 2) spike counts
{
    const int b    = blockIdx.x;
    const int h    = threadIdx.x;
    const int wave = h >> 6;
    const int lane = h & 63;

    __shared__ unsigned long long s_mask[16];    // HRF spikes (prev step)
    __shared__ unsigned long long lif_mask[16];  // LIF spikes (this step)
    __shared__ unsigned int red[16];

    if (h < 16) s_mask[h] = 0ULL;

    float hy = 0.f, hz = 0.f, lifv = 0.f, refp = 0.f;
    float hysum = 0.f, hysq = 0.f;
    unsigned int cnt_hrf = 0, cnt_lif = 0;

    const float g    = gamma_[h];
    const float e    = eps_[h];
    const float bi   = bias[h];
    const float w_in = x2h[h];
    const float ref_decay = expf((float)(-0.042 / 0.25));
    const float* xb = x + (size_t)b * LSTEPS;

    __syncthreads();

    for (int t = 0; t < LSTEPS; ++t) {
        // ---- phase A: cur = x*x2h + s@h2h + bias (sparse row-accumulate) ----
        float cur = xb[t] * w_in + bi;
        for (int w = 0; w < 16; ++w) {
            unsigned long long m = s_mask[w];
            const float* rowbase = h2h + (size_t)(w * 64) * NHID + h;
            while (m) {
                int bit = __ffsll((unsigned long long)m) - 1;
                m &= (m - 1);
                cur += rowbase[(size_t)bit * NHID];
            }
        }

        // ---- phase B: LIF update + spike ----
        lifv = lifv + DTC * (-lifv / TAUM + cur);
        float lif_s = (lifv > THETA) ? 1.f : 0.f;
        lifv = lifv - lif_s * THETA;
        cnt_lif += (unsigned int)lif_s;
        unsigned long long balL = __ballot(lif_s > 0.5f);
        if (lane == 0) lif_mask[wave] = balL;
        __syncthreads();

        // ---- phase C: drive = lif_s @ lif2hrf ----
        float drive = 0.f;
        for (int w = 0; w < 16; ++w) {
            unsigned long long m = lif_mask[w];
            const float* rowbase = lif2hrf + (size_t)(w * 64) * NHID + h;
            while (m) {
                int bit = __ffsll((unsigned long long)m) - 1;
                m &= (m - 1);
                drive += rowbase[(size_t)bit * NHID];
            }
        }

        // ---- phase D: HRF oscillator update + spike + stats ----
        hz = hz + DTC * (drive - g * hy - e * hz);
        hy = hy + DTC * hz;
        float s_new = ((hy - THETA - refp) > 0.f) ? 1.f : 0.f;
        refp = refp * ref_decay + s_new;
        hysum += hy;
        hysq  += hy * hy;
        cnt_hrf += (unsigned int)s_new;
        unsigned long long balS = __ballot(s_new > 0.5f);
        if (lane == 0) s_mask[wave] = balS;   // safe: all threads passed phase A (sync above)
        __syncthreads();                      // visible before next step's phase A
    }

    // ---- epilogue: features ----
    const float Lf   = (float)LSTEPS;
    const float mean = hysum / Lf;
    const float rms  = sqrtf(hysq / Lf + 1e-8f);
    float var = hysq / Lf - mean * mean;
    var = fmaxf(var, 1e-8f);
    const float stdv = sqrtf(var);
    float* ob = out + (size_t)b * (3 * NHID);
    ob[h]            = rms;
    ob[NHID + h]     = stdv;
    ob[2 * NHID + h] = hy;

    // ---- spike-count reduction (exact ints, per-block slot; no atomics) ----
    unsigned int c = cnt_hrf;
    for (int off = 32; off > 0; off >>= 1) c += __shfl_down(c, off, 64);
    if (lane == 0) red[wave] = c;
    __syncthreads();
    if (h == 0) {
        unsigned int tot = 0;
        for (int i = 0; i < 16; ++i) tot += red[i];
        ws[b * 2] = tot;
    }
    __syncthreads();
    c = cnt_lif;
    for (int off = 32; off > 0; off >>= 1) c += __shfl_down(c, off, 64);
    if (lane == 0) red[wave] = c;
    __syncthreads();
    if (h == 0) {
        unsigned int tot = 0;
        for (int i = 0; i < 16; ++i) tot += red[i];
        ws[b * 2 + 1] = tot;
    }
}

__global__ void coesn_final(const unsigned int* __restrict__ ws,
                            float* __restrict__ out)
{
    if (threadIdx.x == 0 && blockIdx.x == 0) {
        unsigned long long hrf = 0, lif = 0;
        for (int b = 0; b < BATCH; ++b) {
            hrf += ws[b * 2];
            lif += ws[b * 2 + 1];
        }
        const float denom = (float)BATCH * (float)LSTEPS * (float)NHID; // exact in f32
        const float r_hrf = (float)hrf / denom;
        const float r_lif = (float)lif / denom;
        float* s = out + (size_t)BATCH * 3 * NHID;
        s[0] = r_hrf;  // r_total (count_lif_spikes=False)
        s[1] = r_hrf;
        s[2] = r_lif;
    }
}

extern "C" void kernel_launch(void* const* d_in, const int* in_sizes, int n_in,
                              void* d_out, int out_size, void* d_ws, size_t ws_size,
                              hipStream_t stream) {
    const float* x       = (const float*)d_in[0];
    const float* x2h     = (const float*)d_in[1];
    const float* h2h     = (const float*)d_in[2];
    const float* bias    = (const float*)d_in[3];
    const float* lif2hrf = (const float*)d_in[4];
    const float* gamma_  = (const float*)d_in[5];
    const float* eps_    = (const float*)d_in[6];
    float* out = (float*)d_out;
    unsigned int* ws = (unsigned int*)d_ws;

    coesn_sim<<<BATCH, NHID, 0, stream>>>(x, x2h, h2h, bias, lif2hrf, gamma_, eps_, out, ws);
    coesn_final<<<1, 64, 0, stream>>>(ws, out);
}